// Round 2
// baseline (113.042 us; speedup 1.0000x reference)
//
#include <hip/hip_runtime.h>
#include <hip/hip_bf16.h>

// Balloon-Windkessel BOLD, explicit Euler, 1000 steps, 4-scalar state.
// Inherently serial recurrence -> single-thread latency-bound kernel.
// Critical path per step: v_log_f32 -> v_mul -> v_exp_f32 -> fma (~30-40 cy).
// R1 fix: reference output dtype is float32 -> d_out is float*, NOT bf16.
//         (R0 wrote bf16; harness read f32 -> garbled pairs, absmax ~= 0.032.)

namespace {
constexpr int   kSteps    = 1000;
constexpr float kDt       = 0.01f;
constexpr float kInvAlpha = 3.125f;          // 1 / 0.32 (exact)
constexpr float kInvRho   = 1.0f / 0.34f;
constexpr float kV0       = 0.02f;
constexpr float kK1       = 7.0f * 0.34f;    // 2.38
constexpr float kK2       = 2.0f;
constexpr float kK3       = 2.0f * 0.34f - 0.2f; // 0.48
constexpr float kLog2OneMinusRho = -0.599462070f; // log2(0.66)
}

__global__ __launch_bounds__(64)
void bold_euler_kernel(const void* __restrict__ mtt_raw,
                       float* __restrict__ out) {
    if (threadIdx.x != 0) return;

    // mtt is a 1-element float32 array (nn.Parameter(1.0)). Keep the
    // defensive bit-sniff: a bf16-payload-in-low-16 would be nonzero.
    unsigned int bits = *(const unsigned int*)mtt_raw;
    float mtt = ((bits & 0xFFFFu) == 0u) ? __uint_as_float(bits)
                                         : __uint_as_float(bits << 16);

    const float inv_mtt = __builtin_amdgcn_rcpf(mtt);
    const float c1 = kDt * inv_mtt;          // dt / mtt

    float s = 0.0f, f = 1.0f, v = 1.0f, q = 1.0f;

    #pragma unroll 5
    for (int i = 0; i < kSteps; ++i) {
        // outflow: v^(1/alpha) = exp2(3.125 * log2(v))  -- the critical chain
        float vp = __builtin_amdgcn_exp2f(kInvAlpha * __builtin_amdgcn_logf(v));
        // oxygen extraction: E = 1 - (1-rho)^(1/f) = 1 - exp2(log2(0.66) / f)
        float rf = __builtin_amdgcn_rcpf(f);
        float E1 = __builtin_amdgcn_exp2f(kLog2OneMinusRho * rf); // (1-rho)^(1/f)
        float rv = __builtin_amdgcn_rcpf(v);

        // Euler updates (u_t = 1, kappa = gamma = 1)
        float s_n = s + kDt * (2.0f - s - f);          // ds = 1 - s - (f-1)
        float f_n = f + kDt * s;
        float v_n = v + c1 * (f - vp);
        // dq = (f*E/rho - vp*q/v)/mtt ;  f*E = f - f*E1
        float q_n = q + c1 * ((f - f * E1) * kInvRho - vp * q * rv);

        // BOLD readout from the *updated* state (matches lax.scan body)
        float rvn = __builtin_amdgcn_rcpf(v_n);
        float y = kV0 * (kK1 * (1.0f - q_n)
                       + kK2 * (1.0f - q_n * rvn)
                       + kK3 * (1.0f - v_n));
        out[i] = y;

        s = s_n; f = f_n; v = v_n; q = q_n;
    }
}

extern "C" void kernel_launch(void* const* d_in, const int* in_sizes, int n_in,
                              void* d_out, int out_size, void* d_ws, size_t ws_size,
                              hipStream_t stream) {
    bold_euler_kernel<<<dim3(1), dim3(64), 0, stream>>>(
        d_in[0], (float*)d_out);
}

// Round 3
// 94.248 us; speedup vs baseline: 1.1994x; 1.1994x over previous
//
#include <hip/hip_runtime.h>
#include <math.h>

// Balloon-Windkessel BOLD, 1000-step Euler. R3 structure:
//  Phase 0 (64 lanes): f_t via exact closed form of the discrete linear (s,f)
//    recurrence  f_t = 2 + r^t(-cos(t*theta) - (1/sqrt3) sin(t*theta));
//    precompute F_t = c1*f_t and B_t = c1/rho * f_t*(1 - 0.66^(1/f_t)) -> LDS.
//  Phase 1 (lane 0): serial (v,q) recurrence with ZERO transcendentals:
//    p ~ v^3.125 tracked multiplicatively via cubic Taylor of (1+dv/v)^3.125,
//    r ~ 1/v tracked by one Newton step. 14 VALU/step (R1 was ~6 trans +
//    20 VALU in-order ~ 180 cy/step measured).
//  Phase 2 (64 lanes): y_t from (v,q) staged in LDS, coalesced store.

namespace {
constexpr int   kSteps  = 1000;
constexpr float kDt     = 0.01f;
constexpr float kInvRho = 1.0f / 0.34f;
constexpr float kV0 = 0.02f, kK1 = 2.38f, kK2 = 2.0f, kK3 = 0.48f;
// discrete-eigen closed-form constants for f_t (dt = 0.01):
constexpr float kLog2R    = -0.0071769251f;   // log2(sqrt(1-dt+dt^2))
constexpr float kTheta    =  0.0087035531f;   // atan2(sqrt3*dt/2, 1-dt/2) rad
constexpr float kCB       = -0.57735026919f;  // -1/sqrt(3)
constexpr float kL2OneMR  = -0.5994620704f;   // log2(1-rho) = log2(0.66)
// Taylor coeffs of (1+x)^3.125
constexpr float kA1 = 3.125f, kA2 = 3.3203125f, kA3 = 1.2451171875f;
}

__global__ __launch_bounds__(64)
void bold_kernel(const void* __restrict__ mtt_raw, float* __restrict__ out) {
    __shared__ float2 FB[kSteps];   // {F_t = c1*f_t, B_t}
    __shared__ float2 VQ[kSteps];   // {v_{t+1}, q_{t+1}}
    const int lane = threadIdx.x;

    unsigned bits = *(const unsigned*)mtt_raw;
    float mtt = ((bits & 0xFFFFu) == 0u) ? __uint_as_float(bits)
                                         : __uint_as_float(bits << 16);
    const float c1 = kDt / mtt;

    // ---- Phase 0: exact f_t + forcing terms, fully parallel ----
    for (int t = lane; t < kSteps; t += 64) {
        float tf  = (float)t;
        float rt  = exp2f(tf * kLog2R);               // r^t
        float ang = tf * kTheta;                      // <= 8.7 rad
        float cs  = cosf(ang), sn = sinf(ang);
        float f   = 2.0f + rt * (kCB * sn - cs);      // exact discrete f_t
        float E1  = exp2f(kL2OneMR / f);              // (1-rho)^(1/f)
        float F   = c1 * f;
        float B   = (c1 * kInvRho) * f * (1.0f - E1);
        FB[t] = make_float2(F, B);
    }
    __syncthreads();

    // ---- Phase 1: serial (v,q), no transcendentals ----
    if (lane == 0) {
        float v = 1.0f, q = 1.0f;
        float p = 1.0f;   // tracks v^3.125
        float r = 1.0f;   // tracks 1/v
        #pragma unroll 8
        for (int t = 0; t < kSteps; ++t) {
            float2 fb = FB[t];
            float d   = fmaf(-c1, p, fb.x);           // c1*(f_t - v^3.125)
            float vn  = v + d;
            float del = d * r;                        // dv/v
            float h   = fmaf(kA3, del, kA2);
            h         = fmaf(h, del, kA1);
            h         = fmaf(h, del, 1.0f);           // (1+del)^3.125
            float pn  = p * h;
            float rn  = r * fmaf(-vn, r, 2.0f);       // Newton 1/vn
            float A   = fmaf(-c1, p * r, 1.0f);       // 1 - c1*vp_t/v_t
            float qn  = fmaf(q, A, fb.y);
            VQ[t] = make_float2(vn, qn);
            v = vn; q = qn; p = pn; r = rn;
        }
    }
    __syncthreads();

    // ---- Phase 2: BOLD readout, fully parallel, coalesced ----
    for (int t = lane; t < kSteps; t += 64) {
        float2 vq = VQ[t];
        float vn = vq.x, qn = vq.y;
        float y = kV0 * (kK1 * (1.0f - qn)
                       + kK2 * (1.0f - qn / vn)
                       + kK3 * (1.0f - vn));
        out[t] = y;
    }
}

extern "C" void kernel_launch(void* const* d_in, const int* in_sizes, int n_in,
                              void* d_out, int out_size, void* d_ws, size_t ws_size,
                              hipStream_t stream) {
    bold_kernel<<<dim3(1), dim3(64), 0, stream>>>(d_in[0], (float*)d_out);
}

// Round 4
// 86.260 us; speedup vs baseline: 1.3105x; 1.0926x over previous
//
#include <hip/hip_runtime.h>
#include <math.h>

// Balloon-Windkessel BOLD, 1000-step Euler. R4:
//  R3 measured 118 cy/step == ds_read latency (~120 cy) -> phase 1 was
//  LDS-latency-bound (one un-overlapped FB[t] read per step), not VALU-bound.
//  Fix: explicit ping-pong register prefetch of FB in 8-step blocks
//  (ds_read_b128), and a shortened 12-VALU step (carry cpr = c1*p*r;
//  quadratic Taylor for (1+dv/v)^3.125 -- error ~5e-7/step, self-correcting).
//  Phases 0/2 on 256 threads; VQ staged as float4 pairs.

namespace {
constexpr int   kSteps  = 1000;
constexpr int   kPairs  = kSteps / 2;       // float4 entries (2 steps each)
constexpr float kDt     = 0.01f;
constexpr float kInvRho = 1.0f / 0.34f;
constexpr float kV0 = 0.02f, kK1 = 2.38f, kK2 = 2.0f, kK3 = 0.48f;
// discrete-eigen closed form for f_t (dt=0.01): f_t = 2 + r^t(-cos - (1/sqrt3) sin)
constexpr float kLog2R    = -0.0071769251f;   // log2(|lambda|)
constexpr float kThetaRev =  0.0013852133f;   // arg(lambda) / (2*pi)  (v_sin units)
constexpr float kCB       = -0.57735026919f;  // -1/sqrt(3)
constexpr float kL2OneMR  = -0.5994620704f;   // log2(0.66)
// quadratic Taylor of (1+x)^3.125
constexpr float kA1 = 3.125f, kA2 = 3.3203125f;
}

__global__ __launch_bounds__(256)
void bold_kernel(const void* __restrict__ mtt_raw, float* __restrict__ out) {
    __shared__ float4 FBs[kPairs];   // {F_2e, B_2e, F_2e+1, B_2e+1}
    __shared__ float4 VQs[kPairs];   // {v, q} pairs for 2 steps
    const int tid = threadIdx.x;

    unsigned bits = *(const unsigned*)mtt_raw;
    float mtt = ((bits & 0xFFFFu) == 0u) ? __uint_as_float(bits)
                                         : __uint_as_float(bits << 16);
    const float c1 = kDt / mtt;

    // ---- Phase 0: exact discrete f_t + forcing terms (parallel, hw trig) ----
    for (int e = tid; e < kPairs; e += 256) {
        float4 fb;
        #pragma unroll
        for (int h = 0; h < 2; ++h) {
            float tf = (float)(2 * e + h);
            float rt = __builtin_amdgcn_exp2f(tf * kLog2R);       // |lambda|^t
            float ar = tf * kThetaRev;                            // revolutions
            float sn = __builtin_amdgcn_sinf(ar);
            float cs = __builtin_amdgcn_cosf(ar);
            float f  = fmaf(rt, fmaf(kCB, sn, -cs), 2.0f);        // exact f_t
            float E1 = __builtin_amdgcn_exp2f(kL2OneMR * __builtin_amdgcn_rcpf(f));
            float F  = c1 * f;                                    // c1*f_t
            float B  = (c1 * kInvRho) * f * (1.0f - E1);          // c1*f*E/rho
            if (h == 0) { fb.x = F; fb.y = B; } else { fb.z = F; fb.w = B; }
        }
        FBs[e] = fb;
    }
    __syncthreads();

    // ---- Phase 1: serial (v,q); 12 VALU/step, prefetched FB blocks ----
    if (tid == 0) {
        float v = 1.0f, q = 1.0f;
        float p = 1.0f;          // tracks v^3.125
        float r = 1.0f;          // tracks 1/v (Newton)
        float cpr = c1;          // c1 * p * r
        auto step = [&](float F, float B, float& vo, float& qo) {
            float del = fmaf(F, r, -cpr);        // dv/v
            float d   = fmaf(-c1, p, F);         // dv
            float g   = fmaf(kA2, del, kA1);
            float pd  = p * del;
            float Aq  = 1.0f - cpr;              // q multiplier
            float pn  = fmaf(pd, g, p);          // p*(1+del)^3.125
            float vn  = v + d;
            float qn  = fmaf(q, Aq, B);
            float t0  = fmaf(-vn, r, 2.0f);
            float rn  = r * t0;                  // Newton 1/vn
            cpr = c1 * (pn * rn);
            v = vn; p = pn; r = rn; q = qn;
            vo = vn; qo = qn;
        };
        auto proc4 = [&](int base, float4 x0, float4 x1, float4 x2, float4 x3) {
            float4 o;
            step(x0.x, x0.y, o.x, o.y); step(x0.z, x0.w, o.z, o.w); VQs[base]     = o;
            step(x1.x, x1.y, o.x, o.y); step(x1.z, x1.w, o.z, o.w); VQs[base + 1] = o;
            step(x2.x, x2.y, o.x, o.y); step(x2.z, x2.w, o.z, o.w); VQs[base + 2] = o;
            step(x3.x, x3.y, o.x, o.y); step(x3.z, x3.w, o.z, o.w); VQs[base + 3] = o;
        };
        // ping-pong register prefetch: 125 blocks of 8 steps (4 float4 each)
        float4 a0 = FBs[0], a1 = FBs[1], a2 = FBs[2], a3 = FBs[3];
        for (int blk = 0; blk < 124; blk += 2) {
            int nb = 4 * blk + 4;
            float4 b0 = FBs[nb], b1 = FBs[nb+1], b2 = FBs[nb+2], b3 = FBs[nb+3];
            proc4(4 * blk, a0, a1, a2, a3);
            a0 = FBs[nb+4]; a1 = FBs[nb+5]; a2 = FBs[nb+6]; a3 = FBs[nb+7];
            proc4(nb, b0, b1, b2, b3);
        }
        proc4(496, a0, a1, a2, a3);   // block 124 (tail)
    }
    __syncthreads();

    // ---- Phase 2: BOLD readout, parallel, float2 coalesced stores ----
    for (int e = tid; e < kPairs; e += 256) {
        float4 vq = VQs[e];
        float y0 = kV0 * (kK1 * (1.0f - vq.y)
                        + kK2 * fmaf(-vq.y, __builtin_amdgcn_rcpf(vq.x), 1.0f)
                        + kK3 * (1.0f - vq.x));
        float y1 = kV0 * (kK1 * (1.0f - vq.w)
                        + kK2 * fmaf(-vq.w, __builtin_amdgcn_rcpf(vq.z), 1.0f)
                        + kK3 * (1.0f - vq.z));
        ((float2*)out)[e] = make_float2(y0, y1);
    }
}

extern "C" void kernel_launch(void* const* d_in, const int* in_sizes, int n_in,
                              void* d_out, int out_size, void* d_ws, size_t ws_size,
                              hipStream_t stream) {
    bold_kernel<<<dim3(1), dim3(256), 0, stream>>>(d_in[0], (float*)d_out);
}